// Round 2
// baseline (177.557 us; speedup 1.0000x reference)
//
#include <hip/hip_runtime.h>

#define BB 4
#define NN 128
#define LK 16384      // n*n
#define DD 64
#define HH 4
#define DHH 16
#define TI 8          // q-rows per block
#define NI (NN/TI)    // 16
#define TL 1024       // l-chunk per block
#define NL (LK/TL)    // 16
#define NTHREADS 256
#define JITER (TL/64) // 16: block covers 64 l (4 waves x 16 l) per j-iter

// ---- mask dtype classification, computed per-wave via ballots ----
// 0 = int32 (0/1 words), 1 = uint8 (byte mask), 2 = float32 (0.0/1.0)
__device__ __forceinline__ int compute_mode(const void* __restrict__ qmask){
  const unsigned int* w = (const unsigned int*)qmask;
  const int t = threadIdx.x & 63;
  int u8 = 0, i32 = 0, f32 = 0;
  #pragma unroll
  for (int rep = 0; rep < 2; ++rep){
    const unsigned int x = w[t + rep*64];   // first 512 B: in-bounds for every dtype
    const bool one  = (x == 1u);
    const bool fone = (x == 0x3f800000u);
    const bool nz   = (x != 0u);
    u8  += __popcll(__ballot(nz && !one && !fone));
    i32 += __popcll(__ballot(one));
    f32 += __popcll(__ballot(fone));
  }
  int mode = 0;
  if (u8 > i32 && u8 > f32) mode = 1;
  else if (f32 > i32) mode = 2;
  return mode;  // wave-uniform
}

__device__ __forceinline__ bool mget(const void* __restrict__ p, int idx, int mode){
  if (mode == 1) return ((const unsigned char*)p)[idx] != 0;
  if (mode == 2) return ((const float*)p)[idx] != 0.0f;
  return ((const int*)p)[idx] != 0;
}

__device__ __forceinline__ float dot16(float4 q0, float4 q1, float4 q2, float4 q3,
                                       float4 k0, float4 k1, float4 k2, float4 k3){
  float d;
  d = q0.x*k0.x;         d = fmaf(q0.y,k0.y,d); d = fmaf(q0.z,k0.z,d); d = fmaf(q0.w,k0.w,d);
  d = fmaf(q1.x,k1.x,d); d = fmaf(q1.y,k1.y,d); d = fmaf(q1.z,k1.z,d); d = fmaf(q1.w,k1.w,d);
  d = fmaf(q2.x,k2.x,d); d = fmaf(q2.y,k2.y,d); d = fmaf(q2.z,k2.z,d); d = fmaf(q2.w,k2.w,d);
  d = fmaf(q3.x,k3.x,d); d = fmaf(q3.y,k3.y,d); d = fmaf(q3.z,k3.z,d); d = fmaf(q3.w,k3.w,d);
  return d;
}

// ---- pass 1: per-(h,row) sum of exp(logit) over this block's l-chunk ----
// lane mapping: l_local = lane&15 (contiguous l), h = lane>>4  => a wave's
// k-loads cover a contiguous 4KB span (16 l x 256B records).
__global__ __launch_bounds__(NTHREADS) void k1_rowsum(
    const float* __restrict__ qA, const float* __restrict__ kA,
    const void* __restrict__ qm, const void* __restrict__ km,
    float* __restrict__ partials)
{
  const int mode = compute_mode(qm);
  const int lc = blockIdx.x;
  const int it = blockIdx.y;
  const int b  = blockIdx.z;
  const int t  = threadIdx.x;
  const int w  = t >> 6;
  const int lane = t & 63;
  const int ll = lane & 15;
  const int h  = lane >> 4;

  // hoist q-row masks (block-uniform)
  bool qv[TI];
  #pragma unroll
  for (int i = 0; i < TI; ++i) qv[i] = mget(qm, b*NN + it*TI + i, mode);

  float s[TI];
  #pragma unroll
  for (int i = 0; i < TI; ++i) s[i] = 0.0f;

  for (int j = 0; j < JITER; ++j){
    const int l  = lc*TL + j*64 + w*16 + ll;
    const int jn = l >> 7, kn = l & 127;
    const bool kv = (jn != kn) && mget(km, b*LK + l, mode);
    const float4* kp = (const float4*)(kA + ((size_t)(b*LK + l))*DD + h*DHH);
    const float4 k0 = kp[0], k1 = kp[1], k2 = kp[2], k3 = kp[3];
    #pragma unroll
    for (int i = 0; i < TI; ++i){
      const int ig = it*TI + i;
      const float4* qp = (const float4*)(qA + ((size_t)(b*NN + ig))*DD + h*DHH);
      const float d = dot16(qp[0], qp[1], qp[2], qp[3], k0, k1, k2, k3);
      const bool valid = kv && (ig != jn) && (ig != kn) && qv[i];
      s[i] += valid ? __expf(d * 0.25f) : 0.0f;
    }
  }

  // reduce over the 16 l-lanes within each h-group
  #pragma unroll
  for (int i = 0; i < TI; ++i){
    float v = s[i];
    #pragma unroll
    for (int off = 8; off > 0; off >>= 1) v += __shfl_xor(v, off);
    s[i] = v;
  }
  __shared__ float red[NTHREADS/64][HH][TI];
  if (ll == 0){
    #pragma unroll
    for (int i = 0; i < TI; ++i) red[w][h][i] = s[i];
  }
  __syncthreads();
  if (t < HH*TI){   // t = h*8 + i
    const int h2 = t >> 3, i2 = t & 7;
    float v = 0.0f;
    #pragma unroll
    for (int ww = 0; ww < NTHREADS/64; ++ww) v += red[ww][h2][i2];
    partials[(((b*NI + it)*NL) + lc)*(HH*TI) + t] = v;
  }
}

// ---- pass 1b: reduce l-chunk partials -> reciprocal row sums ----
__global__ void k1_finalize(const float* __restrict__ partials, float* __restrict__ R){
  const int row = blockIdx.x*blockDim.x + threadIdx.x;   // row = (b*128+i)*4+h
  if (row >= BB*NN*HH) return;
  const int h = row & 3;
  const int i = (row >> 2) & 127;
  const int b = row >> 9;
  const int it = i >> 3, il = i & 7;
  float ssum = 0.0f;
  for (int lc = 0; lc < NL; ++lc)
    ssum += partials[(((b*NI + it)*NL) + lc)*(HH*TI) + h*TI + il];
  R[row] = ssum > 0.0f ? 1.0f/ssum : 0.0f;
}

// ---- pass 2: recompute logits, write normalized alpha ----
__global__ __launch_bounds__(NTHREADS) void k2_emit(
    const float* __restrict__ qA, const float* __restrict__ kA,
    const void* __restrict__ qm, const void* __restrict__ km,
    const float* __restrict__ R, float* __restrict__ out)
{
  const int mode = compute_mode(qm);
  const int lc = blockIdx.x;
  const int it = blockIdx.y;
  const int b  = blockIdx.z;
  const int t  = threadIdx.x;
  const int w  = t >> 6;
  const int lane = t & 63;
  const int ll = lane & 15;
  const int h  = lane >> 4;

  bool qv[TI];
  float rr[TI];
  #pragma unroll
  for (int i = 0; i < TI; ++i){
    const int ig = it*TI + i;
    qv[i] = mget(qm, b*NN + ig, mode);
    rr[i] = R[(b*NN + ig)*HH + h];
  }

  for (int j = 0; j < JITER; ++j){
    const int l  = lc*TL + j*64 + w*16 + ll;
    const int jn = l >> 7, kn = l & 127;
    const bool kv = (jn != kn) && mget(km, b*LK + l, mode);
    const float4* kp = (const float4*)(kA + ((size_t)(b*LK + l))*DD + h*DHH);
    const float4 k0 = kp[0], k1 = kp[1], k2 = kp[2], k3 = kp[3];
    #pragma unroll
    for (int i = 0; i < TI; ++i){
      const int ig = it*TI + i;
      const float4* qp = (const float4*)(qA + ((size_t)(b*NN + ig))*DD + h*DHH);
      const float d = dot16(qp[0], qp[1], qp[2], qp[3], k0, k1, k2, k3);
      const bool valid = kv && (ig != jn) && (ig != kn) && qv[i];
      out[(size_t)((h*BB + b)*NN + ig)*LK + l] = valid ? __expf(d * 0.25f) * rr[i] : 0.0f;
    }
  }
}

extern "C" void kernel_launch(void* const* d_in, const int* in_sizes, int n_in,
                              void* d_out, int out_size, void* d_ws, size_t ws_size,
                              hipStream_t stream)
{
  const float* qA = (const float*)d_in[0];
  const float* kA = (const float*)d_in[1];
  const void*  qm = d_in[2];
  const void*  km = d_in[3];
  float* out = (float*)d_out;

  float* partials = (float*)d_ws;
  const size_t partials_bytes = (size_t)BB*NI*NL*HH*TI*sizeof(float); // 128 KB
  float* R = (float*)((char*)d_ws + partials_bytes);

  dim3 grid(NL, NI, BB);
  k1_rowsum<<<grid, NTHREADS, 0, stream>>>(qA, kA, qm, km, partials);
  k1_finalize<<<(BB*NN*HH + 255)/256, 256, 0, stream>>>(partials, R);
  k2_emit<<<grid, NTHREADS, 0, stream>>>(qA, kA, qm, km, R, out);
}

// Round 3
// 73.012 us; speedup vs baseline: 2.4319x; 2.4319x over previous
//
#include <hip/hip_runtime.h>
#include <math.h>

#define BB 4
#define NN 128
#define LK 16384      // n*n
#define DD 64
#define HH 4
#define DHH 16
#define TI2 32        // q-rows per block
#define L1CH 256      // K1 l-span per block (4 staged chunks of 64)
#define NL1 (LK/L1CH) // 64
#define L2CH 64       // K2 l-span per block
#define NL2 (LK/L2CH) // 256
#define KROWS 64      // staged k rows per chunk
#define KPAD 68       // floats per LDS row (272B: +16B pad -> 8-bank spread)

// ---- mask dtype classification via wave ballots: 0=int32, 1=uint8, 2=float32
__device__ __forceinline__ int compute_mode(const void* __restrict__ qmask){
  const unsigned int* w = (const unsigned int*)qmask;
  const int t = threadIdx.x & 63;
  int u8 = 0, i32 = 0, f32 = 0;
  #pragma unroll
  for (int rep = 0; rep < 2; ++rep){
    const unsigned int x = w[t + rep*64];   // first 512B: in-bounds for every dtype
    const bool one  = (x == 1u);
    const bool fone = (x == 0x3f800000u);
    const bool nz   = (x != 0u);
    u8  += __popcll(__ballot(nz && !one && !fone));
    i32 += __popcll(__ballot(one));
    f32 += __popcll(__ballot(fone));
  }
  int mode = 0;
  if (u8 > i32 && u8 > f32) mode = 1;
  else if (f32 > i32) mode = 2;
  return mode;
}

__device__ __forceinline__ bool mget(const void* __restrict__ p, int idx, int mode){
  if (mode == 1) return ((const unsigned char*)p)[idx] != 0;
  if (mode == 2) return ((const float*)p)[idx] != 0.0f;
  return ((const int*)p)[idx] != 0;
}

__device__ __forceinline__ float dot16(float4 q0, float4 q1, float4 q2, float4 q3,
                                       float4 k0, float4 k1, float4 k2, float4 k3){
  float d;
  d = q0.x*k0.x;         d = fmaf(q0.y,k0.y,d); d = fmaf(q0.z,k0.z,d); d = fmaf(q0.w,k0.w,d);
  d = fmaf(q1.x,k1.x,d); d = fmaf(q1.y,k1.y,d); d = fmaf(q1.z,k1.z,d); d = fmaf(q1.w,k1.w,d);
  d = fmaf(q2.x,k2.x,d); d = fmaf(q2.y,k2.y,d); d = fmaf(q2.z,k2.z,d); d = fmaf(q2.w,k2.w,d);
  d = fmaf(q3.x,k3.x,d); d = fmaf(q3.y,k3.y,d); d = fmaf(q3.z,k3.z,d); d = fmaf(q3.w,k3.w,d);
  return d;
}

// stage KROWS k-records (256B each) into padded LDS; fully coalesced global reads
__device__ __forceinline__ void stage_k(const float* __restrict__ kA, int b, int lbase,
                                        float* __restrict__ ldsK){
  const int t = threadIdx.x;
  const float4* src = (const float4*)(kA + (((size_t)b << 14) + lbase)*DD);
  #pragma unroll
  for (int p = 0; p < 4; ++p){
    const int f = p*256 + t;          // float4 index 0..1023 over 16KB
    const float4 v = src[f];
    *(float4*)(ldsK + (f >> 4)*KPAD + (f & 15)*4) = v;
  }
}

// stage TI2 q-rows, pre-scaled by 1/sqrt(DH)=0.25
__device__ __forceinline__ void stage_q(const float* __restrict__ qA, int b, int ibase,
                                        float* __restrict__ ldsQ){
  const int t = threadIdx.x;
  const float4* src = (const float4*)(qA + ((size_t)(b*NN + ibase))*DD);
  #pragma unroll
  for (int p = 0; p < 2; ++p){
    const int f = p*256 + t;          // 0..511 over 8KB
    float4 v = src[f];
    v.x *= 0.25f; v.y *= 0.25f; v.z *= 0.25f; v.w *= 0.25f;
    *(float4*)(ldsQ + (f >> 4)*DD + (f & 15)*4) = v;
  }
}

// ---- pass 1: per-(h,row) sum of exp over this block's 256-l span ----
__global__ __launch_bounds__(256) void k1_rowsum(
    const float* __restrict__ qA, const float* __restrict__ kA,
    const void* __restrict__ qm, const void* __restrict__ km,
    float* __restrict__ partials)
{
  __shared__ float ldsK[KROWS*KPAD];
  __shared__ float ldsQ[TI2*DD];
  __shared__ float ldsP[HH][TI2];
  const int mode = compute_mode(qm);
  const int lc = blockIdx.x, it = blockIdx.y, b = blockIdx.z;
  const int t = threadIdx.x, w = t >> 6, ll = t & 63;
  const int ibase = it*TI2;

  stage_q(qA, b, ibase, ldsQ);

  float s[TI2];
  #pragma unroll
  for (int i = 0; i < TI2; ++i) s[i] = 0.0f;

  for (int jj = 0; jj < L1CH/KROWS; ++jj){
    if (jj) __syncthreads();                 // prior chunk's readers done
    stage_k(kA, b, lc*L1CH + jj*KROWS, ldsK);
    __syncthreads();

    const int l  = lc*L1CH + jj*KROWS + ll;
    const int jn = l >> 7, kn = l & 127;
    const bool kv = (jn != kn) && mget(km, (b << 14) + l, mode);
    unsigned vmask = kv ? 0xFFFFFFFFu : 0u;
    if ((unsigned)(jn - ibase) < TI2) vmask &= ~(1u << (jn - ibase));
    if ((unsigned)(kn - ibase) < TI2) vmask &= ~(1u << (kn - ibase));

    const float* kp = ldsK + ll*KPAD + w*DHH;   // wave w owns head h=w
    const float4 k0 = *(const float4*)(kp),    k1 = *(const float4*)(kp+4),
                 k2 = *(const float4*)(kp+8),  k3 = *(const float4*)(kp+12);

    #pragma unroll
    for (int i = 0; i < TI2; ++i){              // full unroll: s[i] stays in regs
      const float* qp = ldsQ + i*DD + w*DHH;    // wave-uniform -> broadcast
      float d = dot16(*(const float4*)(qp),   *(const float4*)(qp+4),
                      *(const float4*)(qp+8), *(const float4*)(qp+12),
                      k0, k1, k2, k3);
      d = (vmask & (1u << i)) ? d : -INFINITY;  // exp(-inf)=0 kills invalid elems
      s[i] += __expf(d);
    }
  }

  #pragma unroll
  for (int i = 0; i < TI2; ++i){
    float v = s[i];
    #pragma unroll
    for (int off = 32; off; off >>= 1) v += __shfl_xor(v, off);
    if (ll == 0) ldsP[w][i] = v;
  }
  __syncthreads();
  if (t < HH*TI2){                 // t = h*32 + i
    const int h = t >> 5, i = t & 31;
    const bool qv = mget(qm, b*NN + ibase + i, mode);
    partials[((lc*BB + b)*HH + h)*NN + ibase + i] = qv ? ldsP[h][i] : 0.0f;
  }
}

// ---- pass 1b: reduce partials over lc -> reciprocal row sums ----
__global__ void k1_finalize(const float* __restrict__ partials, float* __restrict__ R){
  const int tid = blockIdx.x*256 + threadIdx.x;   // 0..2047 = (b*4+h)*128+ig
  float ssum = 0.0f;
  for (int lc = 0; lc < NL1; ++lc) ssum += partials[lc*(BB*HH*NN) + tid];
  const int ig = tid & 127, h = (tid >> 7) & 3, b = tid >> 9;
  R[(b*NN + ig)*HH + h] = (ssum > 0.0f) ? 1.0f/ssum : 0.0f;
}

// ---- pass 2: recompute logits, write normalized alpha (coalesced 256B/wave) ----
__global__ __launch_bounds__(256) void k2_emit(
    const float* __restrict__ qA, const float* __restrict__ kA,
    const void* __restrict__ qm, const void* __restrict__ km,
    const float* __restrict__ R, float* __restrict__ out)
{
  __shared__ float ldsK[KROWS*KPAD];
  __shared__ float ldsQ[TI2*DD];
  const int mode = compute_mode(qm);
  const int lc = blockIdx.x, it = blockIdx.y, b = blockIdx.z;
  const int t = threadIdx.x, w = t >> 6, ll = t & 63;
  const int ibase = it*TI2;
  const int lbase = lc*L2CH;

  stage_q(qA, b, ibase, ldsQ);
  stage_k(kA, b, lbase, ldsK);
  __syncthreads();

  const int l  = lbase + ll;
  const int jn = l >> 7, kn = l & 127;
  const bool kv = (jn != kn) && mget(km, (b << 14) + l, mode);
  // NOTE: q-mask omitted here on purpose: masked q-rows have R==0 (K1 zeroes them)
  unsigned vmask = kv ? 0xFFFFFFFFu : 0u;
  if ((unsigned)(jn - ibase) < TI2) vmask &= ~(1u << (jn - ibase));
  if ((unsigned)(kn - ibase) < TI2) vmask &= ~(1u << (kn - ibase));

  const float* kp = ldsK + ll*KPAD + w*DHH;
  const float4 k0 = *(const float4*)(kp),    k1 = *(const float4*)(kp+4),
               k2 = *(const float4*)(kp+8),  k3 = *(const float4*)(kp+12);

  float* op = out + (((size_t)((w*BB + b)*NN + ibase)) << 14) + lbase + ll;
  const float* Rp = R + (b*NN + ibase)*HH + w;

  #pragma unroll 4
  for (int i = 0; i < TI2; ++i){
    const float* qp = ldsQ + i*DD + w*DHH;
    float d = dot16(*(const float4*)(qp),   *(const float4*)(qp+4),
                    *(const float4*)(qp+8), *(const float4*)(qp+12),
                    k0, k1, k2, k3);
    d = (vmask & (1u << i)) ? d : -INFINITY;
    const float r = Rp[i*HH];                 // wave-uniform broadcast load
    op[((size_t)i) << 14] = __expf(d) * r;    // 64 lanes -> 256B contiguous
  }
}

extern "C" void kernel_launch(void* const* d_in, const int* in_sizes, int n_in,
                              void* d_out, int out_size, void* d_ws, size_t ws_size,
                              hipStream_t stream)
{
  const float* qA = (const float*)d_in[0];
  const float* kA = (const float*)d_in[1];
  const void*  qm = d_in[2];
  const void*  km = d_in[3];
  float* out = (float*)d_out;

  float* partials = (float*)d_ws;                    // NL1*BB*HH*NN floats = 512KB
  float* R        = partials + (size_t)NL1*BB*HH*NN; // 2048 floats = 8KB

  dim3 g1(NL1, NN/TI2, BB);        // (64, 4, 4)  = 1024 blocks
  k1_rowsum<<<g1, 256, 0, stream>>>(qA, kA, qm, km, partials);
  k1_finalize<<<(BB*HH*NN)/256, 256, 0, stream>>>(partials, R);
  dim3 g2(NL2, NN/TI2, BB);        // (256, 4, 4) = 4096 blocks
  k2_emit<<<g2, 256, 0, stream>>>(qA, kA, qm, km, R, out);
}